// Round 11
// baseline (170.164 us; speedup 1.0000x reference)
//
#include <hip/hip_runtime.h>
#include <math.h>

namespace {

constexpr int NQ = 10;
constexpr int NL = 4;
constexpr float PI_F = 3.14159265358979323846f;

// One batch element per wave. Packed {re,im} float2 per amp (16 v2 state).
// Complex math via v_pk_fma_f32 op_sel/neg_lo. Lane exchanges:
//   masks 1,2,8  -> DPP (VALU)
//   mask  4      -> ds_swizzle
//   masks 16,32  -> v_permlane16/32_swap_b32 (VALU) via the direction-
//                   agnostic sum trick: with a=b=v, after swap a+b ==
//                   own+partner exactly; gate uses result = cB*sum +
//                   (cA-cB)*own (algebraically identical, same pk count).
// Composed 5-CNOT lane permutation -> ds_bpermute (unavoidable general
// GF(2) lane map). Layer-trailing C(9->0) deferred into next layer's
// wire-0 gate; measurement fixes the final pending swap. Layer 0 uses the
// |0> product-state shortcut (no exchanges at all).

typedef float v2 __attribute__((ext_vector_type(2)));

__device__ __forceinline__ float readlane_f(float v, int lane_const) {
  return __int_as_float(__builtin_amdgcn_readlane(__float_as_int(v), lane_const));
}
__device__ __forceinline__ float bperm_f(int addr4, float v) {
  return __int_as_float(__builtin_amdgcn_ds_bpermute(addr4, __float_as_int(v)));
}

// own + partner(lane^32) via v_permlane32_swap (VALU pipe, no DS).
__device__ __forceinline__ float plsum32(float v) {
  float a = v, b = v;
  asm("v_permlane32_swap_b32 %0, %1" : "+v"(a), "+v"(b));
  return a + b;
}
// own + partner(lane^16) via v_permlane16_swap.
__device__ __forceinline__ float plsum16(float v) {
  float a = v, b = v;
  asm("v_permlane16_swap_b32 %0, %1" : "+v"(a), "+v"(b));
  return a + b;
}
template<int MASK>
__device__ __forceinline__ v2 plsum2(v2 v) {
  v2 r;
  if constexpr (MASK == 32) { r.x = plsum32(v.x); r.y = plsum32(v.y); }
  else                      { r.x = plsum16(v.x); r.y = plsum16(v.y); }
  return r;
}

// xor-lane exchange for masks 1,2,8 (DPP) and 4 (ds_swizzle).
template<int MASK>
__device__ __forceinline__ float lxor(float v) {
  if constexpr (MASK == 1 || MASK == 2 || MASK == 8) {
    constexpr int ctrl = (MASK == 1) ? 0xB1 : (MASK == 2) ? 0x4E : 0x128;
    int i = __float_as_int(v);
    return __int_as_float(__builtin_amdgcn_update_dpp(i, i, ctrl, 0xF, 0xF, true));
  } else {
    return __shfl_xor(v, MASK, 64);
  }
}
template<int MASK>
__device__ __forceinline__ v2 lxor2(v2 v) {
  v2 r; r.x = lxor<MASK>(v.x); r.y = lxor<MASK>(v.y); return r;
}

// d = u (*) a   (complex multiply; packed {re,im})
__device__ __forceinline__ v2 cmul(v2 u, v2 a) {
  v2 d;
  asm("v_pk_mul_f32 %0, %1, %2 op_sel:[0,0] op_sel_hi:[0,1]\n\t"
      "v_pk_fma_f32 %0, %1, %2, %0 op_sel:[1,1,0] op_sel_hi:[1,0,1] neg_lo:[1,0,0]"
      : "=&v"(d) : "v"(u), "v"(a));
  return d;
}
// d = acc + u (*) a
__device__ __forceinline__ v2 cfma(v2 u, v2 a, v2 acc) {
  v2 d;
  asm("v_pk_fma_f32 %0, %1, %2, %3 op_sel:[0,0,0] op_sel_hi:[0,1,1]\n\t"
      "v_pk_fma_f32 %0, %1, %2, %0 op_sel:[1,1,0] op_sel_hi:[1,0,1] neg_lo:[1,0,0]"
      : "=&v"(d) : "v"(u), "v"(a), "v"(acc));
  return d;
}

// Gate on state bit P. SW: pending xor-32 lane swap on odd regs consumed
// here (only legal for P==9).
template<int P, bool SW>
__device__ __forceinline__ void apply_u(v2 (&s)[16],
                                        v2 u00, v2 u01, v2 u10, v2 u11,
                                        int lane) {
  if constexpr (P < 4) {
    constexpr int bit = 1 << P;
#pragma unroll
    for (int r = 0; r < 16; ++r) {
      if ((r & bit) == 0) {
        int r1 = r | bit;
        v2 a0 = s[r], a1 = s[r1];
        s[r]  = cfma(u01, a1, cmul(u00, a0));
        s[r1] = cfma(u11, a1, cmul(u10, a0));
      }
    }
  } else if constexpr (P < 8) {
    constexpr int mask = 1 << (P - 4);
    bool hi = (lane & mask) != 0;
    v2 cA = hi ? u11 : u00;   // own coefficient
    v2 cB = hi ? u10 : u01;   // partner coefficient
#pragma unroll
    for (int r = 0; r < 16; ++r) {
      v2 p = lxor2<mask>(s[r]);
      s[r] = cfma(cB, p, cmul(cA, s[r]));
    }
  } else {
    // masks 16/32 via permlane sum-form: result = cB*sum + (cA-cB)*own.
    constexpr int mask = 1 << (P - 4);
    bool hi = (lane & mask) != 0;
    v2 cA = hi ? u11 : u00;
    v2 cB = hi ? u10 : u01;
    v2 dAB = cA - cB;
    v2 dBA = cB - cA;
#pragma unroll
    for (int r = 0; r < 16; ++r) {
      v2 sum = plsum2<mask>(s[r]);
      if constexpr (SW) {
        if (r & 1) { s[r] = cfma(cA, sum, cmul(dBA, s[r])); continue; }
      }
      s[r] = cfma(cB, sum, cmul(dAB, s[r]));
    }
  }
}

// CNOT chain: (9,8)(8,7)(7,6)(6,5)(5,4) composed bpermute | (4,3) cndmask |
// (3,2)(2,1)(1,0) reg swaps | (0,9) DEFERRED.
__device__ __forceinline__ void cnot_block(v2 (&s)[16], int lane, int srcl4) {
#pragma unroll
  for (int r = 0; r < 16; ++r) {
    s[r].x = bperm_f(srcl4, s[r].x);
    s[r].y = bperm_f(srcl4, s[r].y);
  }
  bool ctrl = (lane & 1) != 0;
#pragma unroll
  for (int r = 0; r < 8; ++r) {
    int r1 = r | 8;
    v2 t0 = s[r], t1 = s[r1];
    s[r]  = ctrl ? t1 : t0;
    s[r1] = ctrl ? t0 : t1;
  }
#pragma unroll
  for (int r = 8; r < 12; ++r) { v2 t = s[r]; s[r] = s[r | 4]; s[r | 4] = t; }
  {
    const int rs[4] = {4, 5, 12, 13};
#pragma unroll
    for (int k = 0; k < 4; ++k) {
      int r = rs[k];
      v2 t = s[r]; s[r] = s[r | 2]; s[r | 2] = t;
    }
  }
#pragma unroll
  for (int r = 2; r < 16; r += 4) { v2 t = s[r]; s[r] = s[r | 1]; s[r | 1] = t; }
}

// Layer 0 on |0>: product state. Wire w (0..5) -> lane bit (5-w);
// wires 6..9 -> reg bits 3..0. amp = prod of column-0 entries.
__device__ __forceinline__ void init_product(v2 (&s)[16], const float4* wmat,
                                             float cx, float sx, int lane) {
  v2 u0, u1;
#define C0(i) { float4 wa = wmat[(i) * 2], wb = wmat[(i) * 2 + 1]; \
    v2 wa0 = {wa.x, wa.y}, wa1 = {wa.z, wa.w}; \
    v2 wb0 = {wb.x, wb.y}, wb1 = {wb.z, wb.w}; \
    float ca = readlane_f(cx, (i)), sa = readlane_f(sx, (i)); \
    u0 = ca * wa0 + sa * wa1; u1 = ca * wb0 + sa * wb1; }
  v2 f;
  C0(0); f = (lane & 32) ? u1 : u0;
  C0(1); f = cmul((lane & 16) ? u1 : u0, f);
  C0(2); f = cmul((lane & 8) ? u1 : u0, f);
  C0(3); f = cmul((lane & 4) ? u1 : u0, f);
  C0(4); f = cmul((lane & 2) ? u1 : u0, f);
  C0(5); f = cmul((lane & 1) ? u1 : u0, f);
  v2 q6_0, q6_1, q7_0, q7_1, q8_0, q8_1, q9_0, q9_1;
  C0(6); q6_0 = u0; q6_1 = u1;
  C0(7); q7_0 = u0; q7_1 = u1;
  C0(8); q8_0 = u0; q8_1 = u1;
  C0(9); q9_0 = u0; q9_1 = u1;
#undef C0
  v2 qa0 = cmul(q8_0, q9_0), qa1 = cmul(q8_0, q9_1);
  v2 qa2 = cmul(q8_1, q9_0), qa3 = cmul(q8_1, q9_1);
  v2 qb0 = cmul(q6_0, q7_0), qb1 = cmul(q6_0, q7_1);
  v2 qb2 = cmul(q6_1, q7_0), qb3 = cmul(q6_1, q7_1);
  v2 fa0 = cmul(qa0, f), fa1 = cmul(qa1, f), fa2 = cmul(qa2, f), fa3 = cmul(qa3, f);
  s[0]  = cmul(qb0, fa0); s[1]  = cmul(qb0, fa1); s[2]  = cmul(qb0, fa2); s[3]  = cmul(qb0, fa3);
  s[4]  = cmul(qb1, fa0); s[5]  = cmul(qb1, fa1); s[6]  = cmul(qb1, fa2); s[7]  = cmul(qb1, fa3);
  s[8]  = cmul(qb2, fa0); s[9]  = cmul(qb2, fa1); s[10] = cmul(qb2, fa2); s[11] = cmul(qb2, fa3);
  s[12] = cmul(qb3, fa0); s[13] = cmul(qb3, fa1); s[14] = cmul(qb3, fa2); s[15] = cmul(qb3, fa3);
}

template<int L, bool PEND>
__device__ __forceinline__ void layer_gates(v2 (&s)[16], const float4* wmat,
                                            float cxv, float sxv, int lane) {
#define FUSED(i, SW) { \
    float4 wa = wmat[(L * NQ + (i)) * 2], wb = wmat[(L * NQ + (i)) * 2 + 1]; \
    float ca = readlane_f(cxv, (i)); \
    float sa = readlane_f(sxv, (i)); \
    v2 wa0 = {wa.x, wa.y}, wa1 = {wa.z, wa.w}; \
    v2 wb0 = {wb.x, wb.y}, wb1 = {wb.z, wb.w}; \
    v2 u00 = ca * wa0 + sa * wa1, u01 = ca * wa1 - sa * wa0; \
    v2 u10 = ca * wb0 + sa * wb1, u11 = ca * wb1 - sa * wb0; \
    apply_u<9 - (i), SW>(s, u00, u01, u10, u11, lane); }
  FUSED(0, PEND)            // wire0 = bit9 = lane xor 32; consumes pending swap
  FUSED(1, false) FUSED(2, false) FUSED(3, false) FUSED(4, false)
  FUSED(5, false) FUSED(6, false) FUSED(7, false) FUSED(8, false) FUSED(9, false)
#undef FUSED
}

__global__ __launch_bounds__(256, 8) void qsim(const float* __restrict__ x,
                                               const float* __restrict__ w,
                                               float* __restrict__ out, int batch) {
  // Batch-shared fused weight matrices W = RZ(w2)*RY(w1)*RZ(w0).
  __shared__ float4 wmat[NL * NQ * 2];
  int tid = threadIdx.x;
  if (tid < NL * NQ) {
    const float* wp = &w[tid * 3];
    float t0 = 0.5f * wp[0], t1 = 0.5f * wp[1], t2 = 0.5f * wp[2];
    float c1, s1; sincosf(t1, &s1, &c1);
    float cA, sA; sincosf(t0 + t2, &sA, &cA);
    float cB, sB; sincosf(t0 - t2, &sB, &cB);
    wmat[tid * 2]     = make_float4(c1 * cA, -c1 * sA, -s1 * cB, -s1 * sB);
    wmat[tid * 2 + 1] = make_float4(s1 * cB, -s1 * sB,  c1 * cA,  c1 * sA);
  }
  __syncthreads();

  int lane = tid & 63;
  int b = blockIdx.x * 4 + (tid >> 6);
  if (b >= batch) return;

  float cxv = 1.0f, sxv = 0.0f;
  if (lane < NQ) {
    float th = tanhf(x[b * NQ + lane]) * PI_F;
    sincosf(0.5f * th, &sxv, &cxv);
  }

  // Composed lane-permutation for the 5 lane-lane CNOTs.
  int srcl4;
  {
    int t = lane;
    t ^= (t >> 1) & 1;
    t ^= ((t >> 2) & 1) << 1;
    t ^= ((t >> 3) & 1) << 2;
    t ^= ((t >> 4) & 1) << 3;
    t ^= ((t >> 5) & 1) << 4;
    srcl4 = t << 2;
  }

  v2 s[16];
  // Layer 0 single-qubit part: direct product state (|0> start), then CNOTs.
  init_product(s, wmat, cxv, sxv, lane);
  cnot_block(s, lane, srcl4);

  layer_gates<1, true>(s, wmat, cxv, sxv, lane);
  cnot_block(s, lane, srcl4);
  layer_gates<2, true>(s, wmat, cxv, sxv, lane);
  cnot_block(s, lane, srcl4);
  layer_gates<3, true>(s, wmat, cxv, sxv, lane);
  cnot_block(s, lane, srcl4);
  // Layer 3's (0,9) still pending: odd regs' amps live at lane^32.

  // Measurement. q=0 (lane bit 5) sign fix for pending swap: totE - totO.
  float prob[16];
  float totE = 0.0f, totO = 0.0f;
#pragma unroll
  for (int r = 0; r < 16; ++r) {
    prob[r] = s[r].x * s[r].x + s[r].y * s[r].y;
    if (r & 1) totO += prob[r]; else totE += prob[r];
  }
  float total = totE + totO;
  float part[10];
#pragma unroll
  for (int p = 0; p < 4; ++p) {
    float acc = 0.0f;
#pragma unroll
    for (int r = 0; r < 16; ++r)
      acc += (r & (1 << p)) ? -prob[r] : prob[r];
    part[p] = acc;
  }
#pragma unroll
  for (int p = 4; p < 9; ++p)
    part[p] = (lane & (1 << (p - 4))) ? -total : total;
  {
    float d = totE - totO;             // pending xor-32 on odd regs
    part[9] = (lane & 32) ? -d : d;
  }

#pragma unroll
  for (int p = 0; p < 10; ++p) {
    float a = part[p];
    a += lxor<1>(a);
    a += lxor<2>(a);
    a += lxor<4>(a);
    a += lxor<8>(a);
    a = plsum16(a);   // xor-16 stage on VALU pipe
    a = plsum32(a);   // xor-32 stage on VALU pipe
    part[p] = a;
  }

  if (lane == 0) {
#pragma unroll
    for (int q = 0; q < NQ; ++q)
      out[b * NQ + q] = part[9 - q];
  }
}

}  // namespace

extern "C" void kernel_launch(void* const* d_in, const int* in_sizes, int n_in,
                              void* d_out, int out_size, void* d_ws, size_t ws_size,
                              hipStream_t stream) {
  const float* x = (const float*)d_in[0];
  const float* w = (const float*)d_in[1];
  float* out = (float*)d_out;
  int batch = in_sizes[0] / NQ;
  int blocks = (batch + 3) / 4;  // 4 waves/block, 1 batch element per wave
  qsim<<<blocks, 256, 0, stream>>>(x, w, out, batch);
}

// Round 14
// 161.442 us; speedup vs baseline: 1.0540x; 1.0540x over previous
//
#include <hip/hip_runtime.h>
#include <math.h>

namespace {

constexpr int NQ = 10;
constexpr int NL = 4;
constexpr float PI_F = 3.14159265358979323846f;

// One batch element per wave (R10 structure, verified 134us). Packed {re,im}
// float2 per amp. SU(2) exploitation: U = W*RY(a) has u11 = conj(u00),
// u10 = -conj(u01), so only u00,u01 are built; the second gate row uses
// conjugated asm variants (cmulc / cfmamc), and lane-gate coefficient
// selects become single sign-bit XORs. Lane exchanges: DPP for masks 1,2,8;
// ds_swizzle for 4,16,32. Composed 5-CNOT lane perm -> ds_bpermute.
// Layer-trailing C(9->0) deferred into next layer's wire-0 gate;
// measurement fixes the final pending swap (q=0 via totE-totO) and uses
// permlane-sum (R11-verified) for the 16/32 butterfly stages.
// Layer 0 uses the |0> product-state shortcut.

typedef float v2 __attribute__((ext_vector_type(2)));

__device__ __forceinline__ float readlane_f(float v, int lane_const) {
  return __int_as_float(__builtin_amdgcn_readlane(__float_as_int(v), lane_const));
}
__device__ __forceinline__ float bperm_f(int addr4, float v) {
  return __int_as_float(__builtin_amdgcn_ds_bpermute(addr4, __float_as_int(v)));
}

// own + partner(lane^MASK) — direction-agnostic sum (R11-verified); used in
// the measurement butterfly only.
__device__ __forceinline__ float plsum32(float v) {
  float a = v, b = v;
  asm("v_permlane32_swap_b32 %0, %1" : "+v"(a), "+v"(b));
  return a + b;
}
__device__ __forceinline__ float plsum16(float v) {
  float a = v, b = v;
  asm("v_permlane16_swap_b32 %0, %1" : "+v"(a), "+v"(b));
  return a + b;
}

// xor-lane exchange for masks 1,2,8 (DPP) and 4,16,32 (ds_swizzle).
template<int MASK>
__device__ __forceinline__ float lxor(float v) {
  if constexpr (MASK == 1 || MASK == 2 || MASK == 8) {
    constexpr int ctrl = (MASK == 1) ? 0xB1 : (MASK == 2) ? 0x4E : 0x128;
    int i = __float_as_int(v);
    return __int_as_float(__builtin_amdgcn_update_dpp(i, i, ctrl, 0xF, 0xF, true));
  } else {
    return __shfl_xor(v, MASK, 64);
  }
}
template<int MASK>
__device__ __forceinline__ v2 lxor2(v2 v) {
  v2 r; r.x = lxor<MASK>(v.x); r.y = lxor<MASK>(v.y); return r;
}

// ---- packed complex arithmetic ({re,im} in one VGPR pair) ----
// d = u (*) a
__device__ __forceinline__ v2 cmul(v2 u, v2 a) {
  v2 d;
  asm("v_pk_mul_f32 %0, %1, %2 op_sel:[0,0] op_sel_hi:[0,1]\n\t"
      "v_pk_fma_f32 %0, %1, %2, %0 op_sel:[1,1,0] op_sel_hi:[1,0,1] neg_lo:[1,0,0]"
      : "=&v"(d) : "v"(u), "v"(a));
  return d;
}
// d = acc + u (*) a
__device__ __forceinline__ v2 cfma(v2 u, v2 a, v2 acc) {
  v2 d;
  asm("v_pk_fma_f32 %0, %1, %2, %3 op_sel:[0,0,0] op_sel_hi:[0,1,1]\n\t"
      "v_pk_fma_f32 %0, %1, %2, %0 op_sel:[1,1,0] op_sel_hi:[1,0,1] neg_lo:[1,0,0]"
      : "=&v"(d) : "v"(u), "v"(a), "v"(acc));
  return d;
}
// d = conj(u) (*) a : lo = u.lo*a.lo + u.hi*a.hi ; hi = u.lo*a.hi - u.hi*a.lo
__device__ __forceinline__ v2 cmulc(v2 u, v2 a) {
  v2 d;
  asm("v_pk_mul_f32 %0, %1, %2 op_sel:[0,0] op_sel_hi:[0,1]\n\t"
      "v_pk_fma_f32 %0, %1, %2, %0 op_sel:[1,1,0] op_sel_hi:[1,0,1] neg_hi:[1,0,0]"
      : "=&v"(d) : "v"(u), "v"(a));
  return d;
}
// d = acc - conj(u) (*) a :
//   lo = acc.lo - u.lo*a.lo - u.hi*a.hi ; hi = acc.hi - u.lo*a.hi + u.hi*a.lo
__device__ __forceinline__ v2 cfmamc(v2 u, v2 a, v2 acc) {
  v2 d;
  asm("v_pk_fma_f32 %0, %1, %2, %3 op_sel:[0,0,0] op_sel_hi:[0,1,1] neg_lo:[1,0,0] neg_hi:[1,0,0]\n\t"
      "v_pk_fma_f32 %0, %1, %2, %0 op_sel:[1,1,0] op_sel_hi:[1,0,1] neg_lo:[1,0,0]"
      : "=&v"(d) : "v"(u), "v"(a), "v"(acc));
  return d;
}

// Gate on state bit P with SU(2) matrix given by u00,u01 only.
// sgn = per-lane sign mask ((lane>>bit)&1)<<31 for this gate's lane bit
// (unused for P<4). SW: pending xor-32 lane swap on odd regs consumed here
// (only legal for P==9).
template<int P, bool SW>
__device__ __forceinline__ void apply_u(v2 (&s)[16], v2 u00, v2 u01, int sgn) {
  if constexpr (P < 4) {
    constexpr int bit = 1 << P;
#pragma unroll
    for (int r = 0; r < 16; ++r) {
      if ((r & bit) == 0) {
        int r1 = r | bit;
        v2 a0 = s[r], a1 = s[r1];
        s[r]  = cfma(u01, a1, cmul(u00, a0));            // u00*a0 + u01*a1
        s[r1] = cfmamc(u01, a0, cmulc(u00, a1));         // conj(u00)*a1 - conj(u01)*a0
      }
    }
  } else {
    constexpr int mask = 1 << (P - 4);
    // hi lane: self = u11 = conj(u00) = {u00.x, -u00.y}
    //          partner = u10 = -conj(u01) = {-u01.x, u01.y}
    // lo lane: self = u00, partner = u01.  One XOR each via sgn.
    v2 cA, cB;
    cA.x = u00.x;
    cA.y = __int_as_float(__float_as_int(u00.y) ^ sgn);
    cB.x = __int_as_float(__float_as_int(u01.x) ^ sgn);
    cB.y = u01.y;
#pragma unroll
    for (int r = 0; r < 16; ++r) {
      v2 p = lxor2<mask>(s[r]);
      if constexpr (SW) {
        if (r & 1) { s[r] = cfma(cA, p, cmul(cB, s[r])); continue; }
      }
      s[r] = cfma(cB, p, cmul(cA, s[r]));
    }
  }
}

// CNOT chain: (9,8)(8,7)(7,6)(6,5)(5,4) composed bpermute | (4,3) cndmask |
// (3,2)(2,1)(1,0) reg swaps | (0,9) DEFERRED.
__device__ __forceinline__ void cnot_block(v2 (&s)[16], int lane, int srcl4) {
#pragma unroll
  for (int r = 0; r < 16; ++r) {
    s[r].x = bperm_f(srcl4, s[r].x);
    s[r].y = bperm_f(srcl4, s[r].y);
  }
  bool ctrl = (lane & 1) != 0;
#pragma unroll
  for (int r = 0; r < 8; ++r) {
    int r1 = r | 8;
    v2 t0 = s[r], t1 = s[r1];
    s[r]  = ctrl ? t1 : t0;
    s[r1] = ctrl ? t0 : t1;
  }
#pragma unroll
  for (int r = 8; r < 12; ++r) { v2 t = s[r]; s[r] = s[r | 4]; s[r | 4] = t; }
  {
    const int rs[4] = {4, 5, 12, 13};
#pragma unroll
    for (int k = 0; k < 4; ++k) {
      int r = rs[k];
      v2 t = s[r]; s[r] = s[r | 2]; s[r | 2] = t;
    }
  }
#pragma unroll
  for (int r = 2; r < 16; r += 4) { v2 t = s[r]; s[r] = s[r | 1]; s[r | 1] = t; }
}

// Layer 0 on |0>: product state. Wire w (0..5) -> lane bit (5-w);
// wires 6..9 -> reg bits 3..0. amp = prod of column-0 entries
// (col0 of U = {u00, u10 = -conj(u01)}).
__device__ __forceinline__ void init_product(v2 (&s)[16], const float4* wmat,
                                             float cx, float sx, int lane) {
  v2 u0, u1;
#define C0(i) { float4 wa = wmat[(i)]; \
    v2 wa0 = {wa.x, wa.y}, wa1 = {wa.z, wa.w}; \
    float ca = readlane_f(cx, (i)), sa = readlane_f(sx, (i)); \
    u0 = ca * wa0 + sa * wa1; \
    v2 t01 = ca * wa1 - sa * wa0; \
    u1.x = -t01.x; u1.y = t01.y; }
  v2 f;
  C0(0); f = (lane & 32) ? u1 : u0;
  C0(1); f = cmul((lane & 16) ? u1 : u0, f);
  C0(2); f = cmul((lane & 8) ? u1 : u0, f);
  C0(3); f = cmul((lane & 4) ? u1 : u0, f);
  C0(4); f = cmul((lane & 2) ? u1 : u0, f);
  C0(5); f = cmul((lane & 1) ? u1 : u0, f);
  v2 q6_0, q6_1, q7_0, q7_1, q8_0, q8_1, q9_0, q9_1;
  C0(6); q6_0 = u0; q6_1 = u1;
  C0(7); q7_0 = u0; q7_1 = u1;
  C0(8); q8_0 = u0; q8_1 = u1;
  C0(9); q9_0 = u0; q9_1 = u1;
#undef C0
  v2 qa0 = cmul(q8_0, q9_0), qa1 = cmul(q8_0, q9_1);
  v2 qa2 = cmul(q8_1, q9_0), qa3 = cmul(q8_1, q9_1);
  v2 qb0 = cmul(q6_0, q7_0), qb1 = cmul(q6_0, q7_1);
  v2 qb2 = cmul(q6_1, q7_0), qb3 = cmul(q6_1, q7_1);
  v2 fa0 = cmul(qa0, f), fa1 = cmul(qa1, f), fa2 = cmul(qa2, f), fa3 = cmul(qa3, f);
  s[0]  = cmul(qb0, fa0); s[1]  = cmul(qb0, fa1); s[2]  = cmul(qb0, fa2); s[3]  = cmul(qb0, fa3);
  s[4]  = cmul(qb1, fa0); s[5]  = cmul(qb1, fa1); s[6]  = cmul(qb1, fa2); s[7]  = cmul(qb1, fa3);
  s[8]  = cmul(qb2, fa0); s[9]  = cmul(qb2, fa1); s[10] = cmul(qb2, fa2); s[11] = cmul(qb2, fa3);
  s[12] = cmul(qb3, fa0); s[13] = cmul(qb3, fa1); s[14] = cmul(qb3, fa2); s[15] = cmul(qb3, fa3);
}

template<int L, bool PEND>
__device__ __forceinline__ void layer_gates(v2 (&s)[16], const float4* wmat,
                                            float cxv, float sxv,
                                            const int (&sgn)[6]) {
  // sgn index: lane-bit k (mask 1<<k) -> sgn[k]; gate i has state bit 9-i,
  // lane bit 5-i for i<6.
#define FUSED(i, SW) { \
    float4 wa = wmat[L * NQ + (i)]; \
    float ca = readlane_f(cxv, (i)); \
    float sa = readlane_f(sxv, (i)); \
    v2 wa0 = {wa.x, wa.y}, wa1 = {wa.z, wa.w}; \
    v2 u00 = ca * wa0 + sa * wa1, u01 = ca * wa1 - sa * wa0; \
    apply_u<9 - (i), SW>(s, u00, u01, ((i) < 6) ? sgn[5 - (i)] : 0); }
  FUSED(0, PEND)            // wire0 = bit9 = lane xor 32; consumes pending swap
  FUSED(1, false) FUSED(2, false) FUSED(3, false) FUSED(4, false)
  FUSED(5, false) FUSED(6, false) FUSED(7, false) FUSED(8, false) FUSED(9, false)
#undef FUSED
}

__global__ __launch_bounds__(256, 8) void qsim(const float* __restrict__ x,
                                               const float* __restrict__ w,
                                               float* __restrict__ out, int batch) {
  // Batch-shared fused weight matrices W = RZ(w2)*RY(w1)*RZ(w0); SU(2), so
  // only the first ROW (w00, w01) is stored.
  __shared__ float4 wmat[NL * NQ];
  int tid = threadIdx.x;
  if (tid < NL * NQ) {
    const float* wp = &w[tid * 3];
    float t0 = 0.5f * wp[0], t1 = 0.5f * wp[1], t2 = 0.5f * wp[2];
    float c1, s1; sincosf(t1, &s1, &c1);
    float cA, sA; sincosf(t0 + t2, &sA, &cA);
    float cB, sB; sincosf(t0 - t2, &sB, &cB);
    // w00 = c1*e^{-iA}; w01 = -s1*e^{+iB}
    wmat[tid] = make_float4(c1 * cA, -c1 * sA, -s1 * cB, -s1 * sB);
  }
  __syncthreads();

  int lane = tid & 63;
  int b = blockIdx.x * 4 + (tid >> 6);
  if (b >= batch) return;

  float cxv = 1.0f, sxv = 0.0f;
  if (lane < NQ) {
    float th = tanhf(x[b * NQ + lane]) * PI_F;
    sincosf(0.5f * th, &sxv, &cxv);
  }

  // Composed lane-permutation for the 5 lane-lane CNOTs.
  int srcl4;
  {
    int t = lane;
    t ^= (t >> 1) & 1;
    t ^= ((t >> 2) & 1) << 1;
    t ^= ((t >> 3) & 1) << 2;
    t ^= ((t >> 4) & 1) << 3;
    t ^= ((t >> 5) & 1) << 4;
    srcl4 = t << 2;
  }

  // Per-lane sign masks: sgn[k] = ((lane>>k)&1) << 31, for lane bit k.
  int sgn[6];
#pragma unroll
  for (int k = 0; k < 6; ++k)
    sgn[k] = (lane & (1 << k)) << (31 - k);

  v2 s[16];
  // Layer 0 single-qubit part: direct product state (|0> start), then CNOTs.
  init_product(s, wmat, cxv, sxv, lane);
  cnot_block(s, lane, srcl4);

  layer_gates<1, true>(s, wmat, cxv, sxv, sgn);
  cnot_block(s, lane, srcl4);
  layer_gates<2, true>(s, wmat, cxv, sxv, sgn);
  cnot_block(s, lane, srcl4);
  layer_gates<3, true>(s, wmat, cxv, sxv, sgn);
  cnot_block(s, lane, srcl4);
  // Layer 3's (0,9) still pending: odd regs' amps live at lane^32.

  // Measurement. q=0 (lane bit 5) sign fix for pending swap: totE - totO.
  float prob[16];
  float totE = 0.0f, totO = 0.0f;
#pragma unroll
  for (int r = 0; r < 16; ++r) {
    prob[r] = s[r].x * s[r].x + s[r].y * s[r].y;
    if (r & 1) totO += prob[r]; else totE += prob[r];
  }
  float total = totE + totO;
  float part[10];
#pragma unroll
  for (int p = 0; p < 4; ++p) {
    float acc = 0.0f;
#pragma unroll
    for (int r = 0; r < 16; ++r)
      acc += (r & (1 << p)) ? -prob[r] : prob[r];
    part[p] = acc;
  }
#pragma unroll
  for (int p = 4; p < 9; ++p)
    part[p] = (lane & (1 << (p - 4))) ? -total : total;
  {
    float d = totE - totO;             // pending xor-32 on odd regs
    part[9] = (lane & 32) ? -d : d;
  }

#pragma unroll
  for (int p = 0; p < 10; ++p) {
    float a = part[p];
    a += lxor<1>(a);
    a += lxor<2>(a);
    a += lxor<4>(a);
    a += lxor<8>(a);
    a = plsum16(a);   // xor-16 stage on VALU pipe (R11-verified sum form)
    a = plsum32(a);   // xor-32 stage on VALU pipe
    part[p] = a;
  }

  if (lane == 0) {
#pragma unroll
    for (int q = 0; q < NQ; ++q)
      out[b * NQ + q] = part[9 - q];
  }
}

}  // namespace

extern "C" void kernel_launch(void* const* d_in, const int* in_sizes, int n_in,
                              void* d_out, int out_size, void* d_ws, size_t ws_size,
                              hipStream_t stream) {
  const float* x = (const float*)d_in[0];
  const float* w = (const float*)d_in[1];
  float* out = (float*)d_out;
  int batch = in_sizes[0] / NQ;
  int blocks = (batch + 3) / 4;  // 4 waves/block, 1 batch element per wave
  qsim<<<blocks, 256, 0, stream>>>(x, w, out, batch);
}